// Round 4
// baseline (449.849 us; speedup 1.0000x reference)
//
#include <hip/hip_runtime.h>

#define BATCH 524288
#define NF 128
#define WPITCH 136   // bf16 elems per LDS row: 128 + 8 pad -> 272 B pitch (16B-aligned)

typedef __attribute__((ext_vector_type(8))) short bf16x8;
typedef __attribute__((ext_vector_type(4))) float f32x4;

__device__ __forceinline__ unsigned short f2bf(float f) {
    union { float f; unsigned u; } c; c.f = f;
    unsigned r = c.u + 0x7fffu + ((c.u >> 16) & 1u);   // round-to-nearest-even
    return (unsigned short)(r >> 16);
}
__device__ __forceinline__ unsigned pk2(float lo, float hi) {
    return (unsigned)f2bf(lo) | ((unsigned)f2bf(hi) << 16);
}

// Block = 4 waves = 64 batch rows (grid = BATCH/64 = 8192, same shape as the
// verified round-0 kernel). Changes vs round-0:
//   * MFMA operands SWAPPED: A = W (from LDS), B = x. With the C/D mapping
//     (col = lane&15, row = quad*4+reg) the output is C[o_local][batch]:
//     each lane holds 4 CONTIGUOUS outputs along o -> float4 stores (8 per
//     lane instead of 32 scalar stores).
//   * Bias folded into the accumulator init -> zero epilogue adds.
__global__ __launch_bounds__(256, 4) void linear_kernel(
    const float* __restrict__ x, const float* __restrict__ w,
    const float* __restrict__ bias, float* __restrict__ out)
{
    __shared__ unsigned short wlds[NF * WPITCH];

    const int tid = threadIdx.x;

    // ---- Stage W (128x128 fp32, row-major [o][i]) -> LDS bf16 ----
    // 4096 float4 / 256 threads = 16 each, coalesced.
    for (int i = tid; i < NF * NF / 4; i += 256) {
        const float4 v = ((const float4*)w)[i];
        const int r = i >> 5;          // 32 float4 per row
        const int c = (i & 31) << 2;
        uint2 pv;
        pv.x = pk2(v.x, v.y);
        pv.y = pk2(v.z, v.w);
        *(uint2*)&wlds[r * WPITCH + c] = pv;   // 8B aligned: 272*r + 2c
    }

    const int lane = tid & 63;
    const int wave = tid >> 6;
    const int bl   = lane & 15;   // fragment row index (both operands); C col = batch lane
    const int quad = lane >> 4;

    // Bias folded into accumulator init: lane's outputs are o = t*16 + quad*4 + r.
    f32x4 bfrag[8];
#pragma unroll
    for (int t = 0; t < 8; t++)
        bfrag[t] = *(const f32x4*)(bias + t * 16 + quad * 4);

    __syncthreads();   // W staged; LDS read-only hereafter

    const size_t row = (size_t)blockIdx.x * 64 + wave * 16 + bl;
    const float* xrow = x + row * NF;

    f32x4 acc[8];
#pragma unroll
    for (int t = 0; t < 8; t++) acc[t] = bfrag[t];

#pragma unroll
    for (int kk = 0; kk < 4; kk++) {
        const int kbase = kk * 32 + quad * 8;

        // x fragment (B operand): 8 contiguous fp32 from this lane's row
        const float4 a0 = *(const float4*)(xrow + kbase);
        const float4 a1 = *(const float4*)(xrow + kbase + 4);
        union { bf16x8 v; unsigned u[4]; } xf;
        xf.u[0] = pk2(a0.x, a0.y);
        xf.u[1] = pk2(a0.z, a0.w);
        xf.u[2] = pk2(a1.x, a1.y);
        xf.u[3] = pk2(a1.z, a1.w);

#pragma unroll
        for (int t = 0; t < 8; t++) {
            // W fragment (A operand): W[o = t*16 + bl][kbase..kbase+7]
            const bf16x8 wf = *(const bf16x8*)&wlds[(t * 16 + bl) * WPITCH + kbase];
            acc[t] = __builtin_amdgcn_mfma_f32_16x16x32_bf16(wf, xf.v, acc[t], 0, 0, 0);
        }
    }

    // ---- Epilogue: lane owns out[row][t*16 + quad*4 .. +3] -> float4 stores ----
    float* orow = out + row * NF + quad * 4;
#pragma unroll
    for (int t = 0; t < 8; t++)
        *(f32x4*)(orow + t * 16) = acc[t];
}

extern "C" void kernel_launch(void* const* d_in, const int* in_sizes, int n_in,
                              void* d_out, int out_size, void* d_ws, size_t ws_size,
                              hipStream_t stream) {
    const float* x    = (const float*)d_in[0];   // enc_x  (524288, 128)
    const float* w    = (const float*)d_in[1];   // weight (128, 128)
    const float* bias = (const float*)d_in[2];   // bias   (128,)
    float* out = (float*)d_out;                  // (524288, 128)

    linear_kernel<<<BATCH / 64, 256, 0, stream>>>(x, w, bias, out);
}